// Round 6
// baseline (548.564 us; speedup 1.0000x reference)
//
#include <hip/hip_runtime.h>

typedef unsigned short ushort_t;
typedef __attribute__((ext_vector_type(8))) short short8;
typedef __attribute__((ext_vector_type(4))) float f32x4;

__device__ inline float bflo(unsigned int u) { return __uint_as_float(u << 16); }
__device__ inline float bfhi(unsigned int u) { return __uint_as_float(u & 0xFFFF0000u); }
__device__ inline unsigned short f2bf(float f) {
    unsigned int u = __float_as_uint(f);
    return (unsigned short)((u + 0x7FFFu + ((u >> 16) & 1u)) >> 16);
}

union U16B { uint4 u; short8 s; };

// ================= CSR build =================
__global__ __launch_bounds__(256) void hist_kernel(const int* __restrict__ dst,
                                                   int* __restrict__ deg, int E) {
    int e = blockIdx.x * 256 + threadIdx.x;
    if (e < E) atomicAdd(&deg[dst[e]], 1);
}

__global__ __launch_bounds__(256) void scan_reduce(const int* __restrict__ deg,
                                                   int* __restrict__ bsum, int n) {
    __shared__ int sdata[256];
    int base = blockIdx.x * 1024 + threadIdx.x * 4;
    int s = 0;
#pragma unroll
    for (int k = 0; k < 4; k++) { int i = base + k; if (i < n) s += deg[i]; }
    sdata[threadIdx.x] = s;
    __syncthreads();
    for (int off = 128; off > 0; off >>= 1) {
        if (threadIdx.x < off) sdata[threadIdx.x] += sdata[threadIdx.x + off];
        __syncthreads();
    }
    if (threadIdx.x == 0) bsum[blockIdx.x] = sdata[0];
}

__global__ void scan_bsum(int* __restrict__ bsum, int nb, int* __restrict__ rowptr, int n) {
    if (threadIdx.x == 0 && blockIdx.x == 0) {
        int acc = 0;
        for (int i = 0; i < nb; i++) { int v = bsum[i]; bsum[i] = acc; acc += v; }
        rowptr[n] = acc;
    }
}

__global__ __launch_bounds__(256) void scan_final(const int* __restrict__ deg,
                                                  const int* __restrict__ bsum,
                                                  int* __restrict__ rowptr, int n) {
    __shared__ int sdata[256];
    int t = threadIdx.x;
    int base = blockIdx.x * 1024 + t * 4;
    int v[4]; int s = 0;
#pragma unroll
    for (int k = 0; k < 4; k++) { int i = base + k; v[k] = (i < n) ? deg[i] : 0; s += v[k]; }
    sdata[t] = s;
    __syncthreads();
    for (int off = 1; off < 256; off <<= 1) {
        int x = 0;
        if (t >= off) x = sdata[t - off];
        __syncthreads();
        if (t >= off) sdata[t] += x;
        __syncthreads();
    }
    int off = bsum[blockIdx.x] + sdata[t] - s;
#pragma unroll
    for (int k = 0; k < 4; k++) {
        int i = base + k;
        if (i < n) { rowptr[i] = off; off += v[k]; }
    }
}

// Pass B: scatter edges into 128-node dst buckets (regions = rowptr[b*128]..)
__global__ __launch_bounds__(256) void scatter_bkt(const int* __restrict__ src,
                                                   const int* __restrict__ dst,
                                                   const int* __restrict__ rowptr,
                                                   int* __restrict__ bctr,
                                                   uint2* __restrict__ ebuf, int E) {
    int e = blockIdx.x * 256 + threadIdx.x;
    if (e >= E) return;
    int d = dst[e], s = src[e];
    int b = d >> 7;
    int base = rowptr[b << 7];
    int p = base + atomicAdd(&bctr[b], 1);
    ebuf[p] = make_uint2((unsigned)s, (unsigned)d);
}

// Pass C: per-bucket LDS counting sort -> final col[]
__global__ __launch_bounds__(256) void sort_bkt(const uint2* __restrict__ ebuf,
                                                const int* __restrict__ rowptr,
                                                int* __restrict__ col, int n) {
    __shared__ int lctr[128];
    int b = blockIdx.x;
    int n0 = b << 7;
    int n1 = min(n0 + 128, n);
    if (threadIdx.x < 128) lctr[threadIdx.x] = 0;
    __syncthreads();
    int r0 = rowptr[n0], r1 = rowptr[n1];
    for (int i = r0 + threadIdx.x; i < r1; i += 256) {
        uint2 ed = ebuf[i];
        int d = (int)ed.y;
        int p = rowptr[d] + atomicAdd(&lctr[d & 127], 1);
        col[p] = (int)ed.x;
    }
}

// ================= MFMA GEMM: Y = bf16(x @ W1) -> two 32-dim planes =================
__global__ __launch_bounds__(256) void gemm_y_mfma(const float* __restrict__ x,
                                                   const float* __restrict__ W1,
                                                   ushort_t* __restrict__ Ylo,
                                                   ushort_t* __restrict__ Yhi, int n) {
    __shared__ ushort_t w1f[4][4][64][8];   // [ks][ct][lane][j]
    __shared__ ushort_t ybuf[64][72];
    for (int i = threadIdx.x; i < 8192; i += 256) {
        int j = i & 7, lane = (i >> 3) & 63, ct = (i >> 9) & 3, ks = (i >> 11) & 3;
        int k = ks * 32 + ((lane >> 4) << 3) + j;
        int c = ct * 16 + (lane & 15);
        w1f[ks][ct][lane][j] = f2bf(W1[k * 64 + c]);
    }
    __syncthreads();
    int w = threadIdx.x >> 6, lane = threadIdx.x & 63;
    int row0 = blockIdx.x * 64;
    int arow = row0 + w * 16 + (lane & 15);
    if (arow >= n) arow = n - 1;
    const float* xr = x + (size_t)arow * 128;
    int k0base = (lane >> 4) << 3;

    f32x4 acc[4] = {{0,0,0,0},{0,0,0,0},{0,0,0,0},{0,0,0,0}};
#pragma unroll
    for (int ks = 0; ks < 4; ks++) {
        int k0 = ks * 32 + k0base;
        float4 aa = *(const float4*)(xr + k0);
        float4 ab = *(const float4*)(xr + k0 + 4);
        U16B af;
        af.u.x = (unsigned int)f2bf(aa.x) | ((unsigned int)f2bf(aa.y) << 16);
        af.u.y = (unsigned int)f2bf(aa.z) | ((unsigned int)f2bf(aa.w) << 16);
        af.u.z = (unsigned int)f2bf(ab.x) | ((unsigned int)f2bf(ab.y) << 16);
        af.u.w = (unsigned int)f2bf(ab.z) | ((unsigned int)f2bf(ab.w) << 16);
#pragma unroll
        for (int ct = 0; ct < 4; ct++) {
            short8 bf = *(const short8*)&w1f[ks][ct][lane][0];
            acc[ct] = __builtin_amdgcn_mfma_f32_16x16x32_bf16(af.s, bf, acc[ct], 0, 0, 0);
        }
    }
#pragma unroll
    for (int ct = 0; ct < 4; ct++)
#pragma unroll
        for (int r = 0; r < 4; r++)
            ybuf[w * 16 + ((lane >> 4) << 2) + r][ct * 16 + (lane & 15)] = f2bf(acc[ct][r]);
    __syncthreads();
    int row = threadIdx.x >> 2, seg = threadIdx.x & 3;
    if (row0 + row < n) {
        const uint4* p = (const uint4*)&ybuf[row][seg * 16];
        uint4 v0 = p[0], v1 = p[1];
        ushort_t* plane = (seg < 2) ? Ylo : Yhi;
        uint4* q = (uint4*)(plane + (size_t)(row0 + row) * 32 + (seg & 1) * 16);
        q[0] = v0; q[1] = v1;
    }
}

// ================= gather on one 32-dim plane (3.2 MB, L2-resident) =================
// 16 node-streams/wave, 4 lanes/node x 16 B = 64 B coalesced rows.
__global__ __launch_bounds__(256) void gather_half(const ushort_t* __restrict__ Ypl,
                                                   const int* __restrict__ rowptr,
                                                   const int* __restrict__ col,
                                                   ushort_t* __restrict__ Zpl, int n) {
    int lane = threadIdx.x & 63;
    int sl = lane & 3;
    int node = blockIdx.x * 64 + (threadIdx.x >> 6) * 16 + (lane >> 2);
    if (node >= n) return;
    int e = rowptr[node], e1 = rowptr[node + 1];
    float a[8];
    {
        uint4 v = *(const uint4*)(Ypl + (size_t)node * 32 + sl * 8);
        a[0] = bflo(v.x); a[1] = bfhi(v.x);
        a[2] = bflo(v.y); a[3] = bfhi(v.y);
        a[4] = bflo(v.z); a[5] = bfhi(v.z);
        a[6] = bflo(v.w); a[7] = bfhi(v.w);
    }
    while (e + 1 < e1) {
        int c0 = col[e], c1 = col[e + 1];
        uint4 v0 = *(const uint4*)(Ypl + (size_t)c0 * 32 + sl * 8);
        uint4 v1 = *(const uint4*)(Ypl + (size_t)c1 * 32 + sl * 8);
        a[0] += bflo(v0.x) + bflo(v1.x); a[1] += bfhi(v0.x) + bfhi(v1.x);
        a[2] += bflo(v0.y) + bflo(v1.y); a[3] += bfhi(v0.y) + bfhi(v1.y);
        a[4] += bflo(v0.z) + bflo(v1.z); a[5] += bfhi(v0.z) + bfhi(v1.z);
        a[6] += bflo(v0.w) + bflo(v1.w); a[7] += bfhi(v0.w) + bfhi(v1.w);
        e += 2;
    }
    if (e < e1) {
        uint4 v0 = *(const uint4*)(Ypl + (size_t)col[e] * 32 + sl * 8);
        a[0] += bflo(v0.x); a[1] += bfhi(v0.x);
        a[2] += bflo(v0.y); a[3] += bfhi(v0.y);
        a[4] += bflo(v0.z); a[5] += bfhi(v0.z);
        a[6] += bflo(v0.w); a[7] += bfhi(v0.w);
    }
    uint4 o;
    o.x = (unsigned int)f2bf(a[0]) | ((unsigned int)f2bf(a[1]) << 16);
    o.y = (unsigned int)f2bf(a[2]) | ((unsigned int)f2bf(a[3]) << 16);
    o.z = (unsigned int)f2bf(a[4]) | ((unsigned int)f2bf(a[5]) << 16);
    o.w = (unsigned int)f2bf(a[6]) | ((unsigned int)f2bf(a[7]) << 16);
    *(uint4*)(Zpl + (size_t)node * 32 + sl * 8) = o;
}

// ================= fused MLP via MFMA =================
template <int HASNEXT>
__global__ __launch_bounds__(256) void fuse_mfma(const ushort_t* __restrict__ Zlo,
                                                 const ushort_t* __restrict__ Zhi,
                                                 const float* __restrict__ b1,
                                                 const float* __restrict__ W2,
                                                 const float* __restrict__ b2,
                                                 const float* __restrict__ Wn,
                                                 ushort_t* __restrict__ Ylo,
                                                 ushort_t* __restrict__ Yhi,
                                                 float* __restrict__ Hout, int n) {
    __shared__ ushort_t w2f[2][4][64][8];
    __shared__ ushort_t wnf[HASNEXT ? 2 : 1][4][64][8];
    __shared__ ushort_t t2[64][72];
    __shared__ float b1s[64], b2s[64];
    for (int i = threadIdx.x; i < 4096; i += 256) {
        int j = i & 7, lane = (i >> 3) & 63, ct = (i >> 9) & 3, ks = (i >> 11) & 1;
        int k = ks * 32 + ((lane >> 4) << 3) + j;
        int c = ct * 16 + (lane & 15);
        w2f[ks][ct][lane][j] = f2bf(W2[k * 64 + c]);
        if (HASNEXT) wnf[ks][ct][lane][j] = f2bf(Wn[k * 64 + c]);
    }
    if (threadIdx.x < 64) { b1s[threadIdx.x] = b1[threadIdx.x]; b2s[threadIdx.x] = b2[threadIdx.x]; }
    __syncthreads();

    int w = threadIdx.x >> 6, lane = threadIdx.x & 63;
    int row0 = blockIdx.x * 64;
    int arow = row0 + w * 16 + (lane & 15);
    if (arow >= n) arow = n - 1;
    int k0base = (lane >> 4) << 3;

    f32x4 acc[4] = {{0,0,0,0},{0,0,0,0},{0,0,0,0},{0,0,0,0}};
#pragma unroll
    for (int ks = 0; ks < 2; ks++) {
        const ushort_t* zr = (ks == 0) ? Zlo : Zhi;
        int k0 = ks * 32 + k0base;
        uint4 zv = *(const uint4*)(zr + (size_t)arow * 32 + k0base);
        float e0 = fmaxf(bflo(zv.x) + b1s[k0 + 0], 0.0f);
        float e1 = fmaxf(bfhi(zv.x) + b1s[k0 + 1], 0.0f);
        float e2 = fmaxf(bflo(zv.y) + b1s[k0 + 2], 0.0f);
        float e3 = fmaxf(bfhi(zv.y) + b1s[k0 + 3], 0.0f);
        float e4 = fmaxf(bflo(zv.z) + b1s[k0 + 4], 0.0f);
        float e5 = fmaxf(bfhi(zv.z) + b1s[k0 + 5], 0.0f);
        float e6 = fmaxf(bflo(zv.w) + b1s[k0 + 6], 0.0f);
        float e7 = fmaxf(bfhi(zv.w) + b1s[k0 + 7], 0.0f);
        U16B af;
        af.u.x = (unsigned int)f2bf(e0) | ((unsigned int)f2bf(e1) << 16);
        af.u.y = (unsigned int)f2bf(e2) | ((unsigned int)f2bf(e3) << 16);
        af.u.z = (unsigned int)f2bf(e4) | ((unsigned int)f2bf(e5) << 16);
        af.u.w = (unsigned int)f2bf(e6) | ((unsigned int)f2bf(e7) << 16);
#pragma unroll
        for (int ct = 0; ct < 4; ct++) {
            short8 bf = *(const short8*)&w2f[ks][ct][lane][0];
            acc[ct] = __builtin_amdgcn_mfma_f32_16x16x32_bf16(af.s, bf, acc[ct], 0, 0, 0);
        }
    }

    int colb = lane & 15;
    if (HASNEXT) {
#pragma unroll
        for (int ct = 0; ct < 4; ct++)
#pragma unroll
            for (int r = 0; r < 4; r++) {
                float v = fmaxf(acc[ct][r] + b2s[ct * 16 + colb], 0.0f);
                t2[w * 16 + ((lane >> 4) << 2) + r][ct * 16 + colb] = f2bf(v);
            }
        __syncthreads();
        f32x4 acc2[4] = {{0,0,0,0},{0,0,0,0},{0,0,0,0},{0,0,0,0}};
#pragma unroll
        for (int ks = 0; ks < 2; ks++) {
            short8 af2 = *(const short8*)&t2[w * 16 + (lane & 15)][ks * 32 + k0base];
#pragma unroll
            for (int ct = 0; ct < 4; ct++) {
                short8 bf = *(const short8*)&wnf[ks][ct][lane][0];
                acc2[ct] = __builtin_amdgcn_mfma_f32_16x16x32_bf16(af2, bf, acc2[ct], 0, 0, 0);
            }
        }
        __syncthreads();
#pragma unroll
        for (int ct = 0; ct < 4; ct++)
#pragma unroll
            for (int r = 0; r < 4; r++)
                t2[w * 16 + ((lane >> 4) << 2) + r][ct * 16 + colb] = f2bf(acc2[ct][r]);
        __syncthreads();
        int row = threadIdx.x >> 2, seg = threadIdx.x & 3;
        if (row0 + row < n) {
            const uint4* p = (const uint4*)&t2[row][seg * 16];
            uint4 v0 = p[0], v1 = p[1];
            ushort_t* plane = (seg < 2) ? Ylo : Yhi;
            uint4* q = (uint4*)(plane + (size_t)(row0 + row) * 32 + (seg & 1) * 16);
            q[0] = v0; q[1] = v1;
        }
    } else {
#pragma unroll
        for (int ct = 0; ct < 4; ct++)
#pragma unroll
            for (int r = 0; r < 4; r++) {
                int row = row0 + w * 16 + ((lane >> 4) << 2) + r;
                if (row < n) {
                    float v = fmaxf(acc[ct][r] + b2s[ct * 16 + colb], 0.0f);
                    Hout[(size_t)row * 64 + ct * 16 + colb] = v;
                }
            }
    }
}

// ================= mean pool, exploiting sorted batch =================
__global__ __launch_bounds__(64) void pool_sorted(const float* __restrict__ h,
                                                  const int* __restrict__ batch,
                                                  float* __restrict__ sums,
                                                  int* __restrict__ cnt, int n) {
    int lane = threadIdx.x;
    int start = blockIdx.x * 64;
    int end = min(start + 64, n);
    if (start >= end) return;
    int cur = batch[start];
    float acc = 0.0f;
    int c = 0;
    for (int i = start; i < end; i++) {
        int b = batch[i];
        if (b != cur) {
            atomicAdd(&sums[cur * 64 + lane], acc);
            if (lane == 0) atomicAdd(&cnt[cur], c);
            acc = 0.0f; c = 0; cur = b;
        }
        acc += h[(size_t)i * 64 + lane];
        c++;
    }
    atomicAdd(&sums[cur * 64 + lane], acc);
    if (lane == 0) atomicAdd(&cnt[cur], c);
}

// ================= finalize =================
__global__ __launch_bounds__(64) void finalize_kernel(const float* __restrict__ sums,
                                                      const int* __restrict__ cnt,
                                                      const float* __restrict__ Wl,
                                                      const float* __restrict__ bl,
                                                      float* __restrict__ out, int G) {
    int g = blockIdx.x;
    int j = threadIdx.x;
    __shared__ float gs[64];
    float c = (float)max(cnt[g], 1);
    float v = sums[g * 64 + j] / c;
    gs[j] = v;
    out[G * 2 + g * 64 + j] = v;
    __syncthreads();
    if (j < 2) {
        float acc = bl[j];
#pragma unroll
        for (int k = 0; k < 64; k++) acc += gs[k] * Wl[k * 2 + j];
        out[g * 2 + j] = acc;
    }
}

extern "C" void kernel_launch(void* const* d_in, const int* in_sizes, int n_in,
                              void* d_out, int out_size, void* d_ws, size_t ws_size,
                              hipStream_t stream) {
    const float* x     = (const float*)d_in[0];
    const int*   ei    = (const int*)d_in[1];
    const int*   batch = (const int*)d_in[2];
    const float* W1_0 = (const float*)d_in[3];
    const float* b1_0 = (const float*)d_in[4];
    const float* W2_0 = (const float*)d_in[5];
    const float* b2_0 = (const float*)d_in[6];
    const float* W1_1 = (const float*)d_in[7];
    const float* b1_1 = (const float*)d_in[8];
    const float* W2_1 = (const float*)d_in[9];
    const float* b2_1 = (const float*)d_in[10];
    const float* W1_2 = (const float*)d_in[11];
    const float* b1_2 = (const float*)d_in[12];
    const float* W2_2 = (const float*)d_in[13];
    const float* b2_2 = (const float*)d_in[14];
    const float* Wl   = (const float*)d_in[15];
    const float* bl   = (const float*)d_in[16];

    const int N = in_sizes[0] / 128;
    const int E = in_sizes[1] / 2;
    const int G = out_size / 66;
    const int* src = ei;
    const int* dst = ei + E;
    float* out = (float*)d_out;

    const int NBK = (N + 127) >> 7;
    const int nb = (N + 1023) / 1024;

    // ---- workspace layout ----
    float* H      = (float*)d_ws;                       // N*64 f32
    ushort_t* Ylo = (ushort_t*)(H + (size_t)N * 64);    // N*32 bf16
    ushort_t* Yhi = Ylo + (size_t)N * 32;
    ushort_t* Zlo = Yhi + (size_t)N * 32;
    ushort_t* Zhi = Zlo + (size_t)N * 32;
    uint2* ebuf   = (uint2*)(Zhi + (size_t)N * 32);     // E uint2
    float* sums   = (float*)(ebuf + (size_t)E);         // G*64
    int*   cnt    = (int*)(sums + (size_t)G * 64);      // G
    int*   deg    = cnt + G;                            // N
    int*   bctr   = deg + N;                            // NBK
    int*   rowptr = bctr + NBK;                         // N+1
    int*   col    = rowptr + (N + 1);                   // E
    int*   bsum   = col + E;                            // nb

    // ---- zero: sums|cnt|deg|bctr contiguous -> one memset ----
    hipMemsetAsync(sums, 0, ((size_t)G * 64 + G + N + NBK) * sizeof(int), stream);

    // ---- CSR build via bucket sort ----
    hist_kernel<<<(E + 255) / 256, 256, 0, stream>>>(dst, deg, E);
    scan_reduce<<<nb, 256, 0, stream>>>(deg, bsum, N);
    scan_bsum<<<1, 64, 0, stream>>>(bsum, nb, rowptr, N);
    scan_final<<<nb, 256, 0, stream>>>(deg, bsum, rowptr, N);
    scatter_bkt<<<(E + 255) / 256, 256, 0, stream>>>(src, dst, rowptr, bctr, ebuf, E);
    sort_bkt<<<NBK, 256, 0, stream>>>(ebuf, rowptr, col, N);

    const int mblk = (N + 63) / 64;

    // ---- layer 0 ----
    gemm_y_mfma<<<mblk, 256, 0, stream>>>(x, W1_0, Ylo, Yhi, N);
    gather_half<<<mblk, 256, 0, stream>>>(Ylo, rowptr, col, Zlo, N);
    gather_half<<<mblk, 256, 0, stream>>>(Yhi, rowptr, col, Zhi, N);
    fuse_mfma<1><<<mblk, 256, 0, stream>>>(Zlo, Zhi, b1_0, W2_0, b2_0, W1_1, Ylo, Yhi, nullptr, N);
    // ---- layer 1 ----
    gather_half<<<mblk, 256, 0, stream>>>(Ylo, rowptr, col, Zlo, N);
    gather_half<<<mblk, 256, 0, stream>>>(Yhi, rowptr, col, Zhi, N);
    fuse_mfma<1><<<mblk, 256, 0, stream>>>(Zlo, Zhi, b1_1, W2_1, b2_1, W1_2, Ylo, Yhi, nullptr, N);
    // ---- layer 2 ----
    gather_half<<<mblk, 256, 0, stream>>>(Ylo, rowptr, col, Zlo, N);
    gather_half<<<mblk, 256, 0, stream>>>(Yhi, rowptr, col, Zhi, N);
    fuse_mfma<0><<<mblk, 256, 0, stream>>>(Zlo, Zhi, b1_2, W2_2, b2_2, nullptr, nullptr, nullptr, H, N);
    // ---- pool + head ----
    pool_sorted<<<(N + 63) / 64, 64, 0, stream>>>(H, batch, sums, cnt, N);
    finalize_kernel<<<G, 64, 0, stream>>>(sums, cnt, Wl, bl, out, G);
}

// Round 7
// 243.208 us; speedup vs baseline: 2.2555x; 2.2555x over previous
//
#include <hip/hip_runtime.h>

typedef unsigned short ushort_t;
typedef __attribute__((ext_vector_type(8))) short short8;
typedef __attribute__((ext_vector_type(4))) float f32x4;

__device__ inline float bflo(unsigned int u) { return __uint_as_float(u << 16); }
__device__ inline float bfhi(unsigned int u) { return __uint_as_float(u & 0xFFFF0000u); }
__device__ inline unsigned short f2bf(float f) {
    unsigned int u = __float_as_uint(f);
    return (unsigned short)((u + 0x7FFFu + ((u >> 16) & 1u)) >> 16);
}

union U16B { uint4 u; short8 s; };

// ================= CSR build =================
// hist + per-edge rank in one pass
__global__ __launch_bounds__(256) void hist_rank(const int* __restrict__ dst,
                                                 int* __restrict__ deg,
                                                 int* __restrict__ rank, int E) {
    int e = blockIdx.x * 256 + threadIdx.x;
    if (e < E) rank[e] = atomicAdd(&deg[dst[e]], 1);
}

__global__ __launch_bounds__(256) void scan_reduce(const int* __restrict__ deg,
                                                   int* __restrict__ bsum, int n) {
    __shared__ int sdata[256];
    int base = blockIdx.x * 1024 + threadIdx.x * 4;
    int s = 0;
#pragma unroll
    for (int k = 0; k < 4; k++) { int i = base + k; if (i < n) s += deg[i]; }
    sdata[threadIdx.x] = s;
    __syncthreads();
    for (int off = 128; off > 0; off >>= 1) {
        if (threadIdx.x < off) sdata[threadIdx.x] += sdata[threadIdx.x + off];
        __syncthreads();
    }
    if (threadIdx.x == 0) bsum[blockIdx.x] = sdata[0];
}

__global__ void scan_bsum(int* __restrict__ bsum, int nb, int* __restrict__ rowptr, int n) {
    if (threadIdx.x == 0 && blockIdx.x == 0) {
        int acc = 0;
        for (int i = 0; i < nb; i++) { int v = bsum[i]; bsum[i] = acc; acc += v; }
        rowptr[n] = acc;
    }
}

__global__ __launch_bounds__(256) void scan_final(const int* __restrict__ deg,
                                                  const int* __restrict__ bsum,
                                                  int* __restrict__ rowptr, int n) {
    __shared__ int sdata[256];
    int t = threadIdx.x;
    int base = blockIdx.x * 1024 + t * 4;
    int v[4]; int s = 0;
#pragma unroll
    for (int k = 0; k < 4; k++) { int i = base + k; v[k] = (i < n) ? deg[i] : 0; s += v[k]; }
    sdata[t] = s;
    __syncthreads();
    for (int off = 1; off < 256; off <<= 1) {
        int x = 0;
        if (t >= off) x = sdata[t - off];
        __syncthreads();
        if (t >= off) sdata[t] += x;
        __syncthreads();
    }
    int off = bsum[blockIdx.x] + sdata[t] - s;
#pragma unroll
    for (int k = 0; k < 4; k++) {
        int i = base + k;
        if (i < n) { rowptr[i] = off; off += v[k]; }
    }
}

// Range-partitioned fill: block's dst-range = blockIdx&7 (~XCD under round-robin
// dispatch). col-slice per range ~0.5 MB -> L2-resident, dirty lines coalesce.
// Slot rowptr[d]+rank[e] is unique per edge -> correct under ANY block placement.
__global__ __launch_bounds__(256) void fill_range(const int* __restrict__ src,
                                                  const int* __restrict__ dst,
                                                  const int* __restrict__ rank,
                                                  const int* __restrict__ rowptr,
                                                  int* __restrict__ col, int E, int CE) {
    int range = blockIdx.x & 7;
    int sub = blockIdx.x >> 3;
    int e0 = sub * CE;
    int e1 = min(e0 + CE, E);
    for (int e = e0 + threadIdx.x; e < e1; e += 256) {
        int d = dst[e];
        if ((d >> 13) == range) col[rowptr[d] + rank[e]] = src[e];
    }
}

// ================= MFMA GEMM: Y = bf16(x @ W1) -> two 32-dim planes =================
__global__ __launch_bounds__(256) void gemm_y_mfma(const float* __restrict__ x,
                                                   const float* __restrict__ W1,
                                                   ushort_t* __restrict__ Ylo,
                                                   ushort_t* __restrict__ Yhi, int n) {
    __shared__ ushort_t w1f[4][4][64][8];   // [ks][ct][lane][j]
    __shared__ ushort_t ybuf[64][72];
    for (int i = threadIdx.x; i < 8192; i += 256) {
        int j = i & 7, lane = (i >> 3) & 63, ct = (i >> 9) & 3, ks = (i >> 11) & 3;
        int k = ks * 32 + ((lane >> 4) << 3) + j;
        int c = ct * 16 + (lane & 15);
        w1f[ks][ct][lane][j] = f2bf(W1[k * 64 + c]);
    }
    __syncthreads();
    int w = threadIdx.x >> 6, lane = threadIdx.x & 63;
    int row0 = blockIdx.x * 64;
    int arow = row0 + w * 16 + (lane & 15);
    if (arow >= n) arow = n - 1;
    const float* xr = x + (size_t)arow * 128;
    int k0base = (lane >> 4) << 3;

    f32x4 acc[4] = {{0,0,0,0},{0,0,0,0},{0,0,0,0},{0,0,0,0}};
#pragma unroll
    for (int ks = 0; ks < 4; ks++) {
        int k0 = ks * 32 + k0base;
        float4 aa = *(const float4*)(xr + k0);
        float4 ab = *(const float4*)(xr + k0 + 4);
        U16B af;
        af.u.x = (unsigned int)f2bf(aa.x) | ((unsigned int)f2bf(aa.y) << 16);
        af.u.y = (unsigned int)f2bf(aa.z) | ((unsigned int)f2bf(aa.w) << 16);
        af.u.z = (unsigned int)f2bf(ab.x) | ((unsigned int)f2bf(ab.y) << 16);
        af.u.w = (unsigned int)f2bf(ab.z) | ((unsigned int)f2bf(ab.w) << 16);
#pragma unroll
        for (int ct = 0; ct < 4; ct++) {
            short8 bf = *(const short8*)&w1f[ks][ct][lane][0];
            acc[ct] = __builtin_amdgcn_mfma_f32_16x16x32_bf16(af.s, bf, acc[ct], 0, 0, 0);
        }
    }
#pragma unroll
    for (int ct = 0; ct < 4; ct++)
#pragma unroll
        for (int r = 0; r < 4; r++)
            ybuf[w * 16 + ((lane >> 4) << 2) + r][ct * 16 + (lane & 15)] = f2bf(acc[ct][r]);
    __syncthreads();
    int row = threadIdx.x >> 2, seg = threadIdx.x & 3;
    if (row0 + row < n) {
        const uint4* p = (const uint4*)&ybuf[row][seg * 16];
        uint4 v0 = p[0], v1 = p[1];
        ushort_t* plane = (seg < 2) ? Ylo : Yhi;
        uint4* q = (uint4*)(plane + (size_t)(row0 + row) * 32 + (seg & 1) * 16);
        q[0] = v0; q[1] = v1;
    }
}

// ================= gather on one 32-dim plane (3.2 MB, L2-friendly) =================
__global__ __launch_bounds__(256) void gather_half(const ushort_t* __restrict__ Ypl,
                                                   const int* __restrict__ rowptr,
                                                   const int* __restrict__ col,
                                                   ushort_t* __restrict__ Zpl, int n) {
    int lane = threadIdx.x & 63;
    int sl = lane & 3;
    int node = blockIdx.x * 64 + (threadIdx.x >> 6) * 16 + (lane >> 2);
    if (node >= n) return;
    int e = rowptr[node], e1 = rowptr[node + 1];
    float a[8];
    {
        uint4 v = *(const uint4*)(Ypl + (size_t)node * 32 + sl * 8);
        a[0] = bflo(v.x); a[1] = bfhi(v.x);
        a[2] = bflo(v.y); a[3] = bfhi(v.y);
        a[4] = bflo(v.z); a[5] = bfhi(v.z);
        a[6] = bflo(v.w); a[7] = bfhi(v.w);
    }
    while (e + 1 < e1) {
        int c0 = col[e], c1 = col[e + 1];
        uint4 v0 = *(const uint4*)(Ypl + (size_t)c0 * 32 + sl * 8);
        uint4 v1 = *(const uint4*)(Ypl + (size_t)c1 * 32 + sl * 8);
        a[0] += bflo(v0.x) + bflo(v1.x); a[1] += bfhi(v0.x) + bfhi(v1.x);
        a[2] += bflo(v0.y) + bflo(v1.y); a[3] += bfhi(v0.y) + bfhi(v1.y);
        a[4] += bflo(v0.z) + bflo(v1.z); a[5] += bfhi(v0.z) + bfhi(v1.z);
        a[6] += bflo(v0.w) + bflo(v1.w); a[7] += bfhi(v0.w) + bfhi(v1.w);
        e += 2;
    }
    if (e < e1) {
        uint4 v0 = *(const uint4*)(Ypl + (size_t)col[e] * 32 + sl * 8);
        a[0] += bflo(v0.x); a[1] += bfhi(v0.x);
        a[2] += bflo(v0.y); a[3] += bfhi(v0.y);
        a[4] += bflo(v0.z); a[5] += bfhi(v0.z);
        a[6] += bflo(v0.w); a[7] += bfhi(v0.w);
    }
    uint4 o;
    o.x = (unsigned int)f2bf(a[0]) | ((unsigned int)f2bf(a[1]) << 16);
    o.y = (unsigned int)f2bf(a[2]) | ((unsigned int)f2bf(a[3]) << 16);
    o.z = (unsigned int)f2bf(a[4]) | ((unsigned int)f2bf(a[5]) << 16);
    o.w = (unsigned int)f2bf(a[6]) | ((unsigned int)f2bf(a[7]) << 16);
    *(uint4*)(Zpl + (size_t)node * 32 + sl * 8) = o;
}

// ================= fused MLP via MFMA =================
template <int HASNEXT>
__global__ __launch_bounds__(256) void fuse_mfma(const ushort_t* __restrict__ Zlo,
                                                 const ushort_t* __restrict__ Zhi,
                                                 const float* __restrict__ b1,
                                                 const float* __restrict__ W2,
                                                 const float* __restrict__ b2,
                                                 const float* __restrict__ Wn,
                                                 ushort_t* __restrict__ Ylo,
                                                 ushort_t* __restrict__ Yhi,
                                                 float* __restrict__ Hout, int n) {
    __shared__ ushort_t w2f[2][4][64][8];
    __shared__ ushort_t wnf[HASNEXT ? 2 : 1][4][64][8];
    __shared__ ushort_t t2[64][72];
    __shared__ float b1s[64], b2s[64];
    for (int i = threadIdx.x; i < 4096; i += 256) {
        int j = i & 7, lane = (i >> 3) & 63, ct = (i >> 9) & 3, ks = (i >> 11) & 1;
        int k = ks * 32 + ((lane >> 4) << 3) + j;
        int c = ct * 16 + (lane & 15);
        w2f[ks][ct][lane][j] = f2bf(W2[k * 64 + c]);
        if (HASNEXT) wnf[ks][ct][lane][j] = f2bf(Wn[k * 64 + c]);
    }
    if (threadIdx.x < 64) { b1s[threadIdx.x] = b1[threadIdx.x]; b2s[threadIdx.x] = b2[threadIdx.x]; }
    __syncthreads();

    int w = threadIdx.x >> 6, lane = threadIdx.x & 63;
    int row0 = blockIdx.x * 64;
    int arow = row0 + w * 16 + (lane & 15);
    if (arow >= n) arow = n - 1;
    int k0base = (lane >> 4) << 3;

    f32x4 acc[4] = {{0,0,0,0},{0,0,0,0},{0,0,0,0},{0,0,0,0}};
#pragma unroll
    for (int ks = 0; ks < 2; ks++) {
        const ushort_t* zr = (ks == 0) ? Zlo : Zhi;
        int k0 = ks * 32 + k0base;
        uint4 zv = *(const uint4*)(zr + (size_t)arow * 32 + k0base);
        float e0 = fmaxf(bflo(zv.x) + b1s[k0 + 0], 0.0f);
        float e1 = fmaxf(bfhi(zv.x) + b1s[k0 + 1], 0.0f);
        float e2 = fmaxf(bflo(zv.y) + b1s[k0 + 2], 0.0f);
        float e3 = fmaxf(bfhi(zv.y) + b1s[k0 + 3], 0.0f);
        float e4 = fmaxf(bflo(zv.z) + b1s[k0 + 4], 0.0f);
        float e5 = fmaxf(bfhi(zv.z) + b1s[k0 + 5], 0.0f);
        float e6 = fmaxf(bflo(zv.w) + b1s[k0 + 6], 0.0f);
        float e7 = fmaxf(bfhi(zv.w) + b1s[k0 + 7], 0.0f);
        U16B af;
        af.u.x = (unsigned int)f2bf(e0) | ((unsigned int)f2bf(e1) << 16);
        af.u.y = (unsigned int)f2bf(e2) | ((unsigned int)f2bf(e3) << 16);
        af.u.z = (unsigned int)f2bf(e4) | ((unsigned int)f2bf(e5) << 16);
        af.u.w = (unsigned int)f2bf(e6) | ((unsigned int)f2bf(e7) << 16);
#pragma unroll
        for (int ct = 0; ct < 4; ct++) {
            short8 bf = *(const short8*)&w2f[ks][ct][lane][0];
            acc[ct] = __builtin_amdgcn_mfma_f32_16x16x32_bf16(af.s, bf, acc[ct], 0, 0, 0);
        }
    }

    int colb = lane & 15;
    if (HASNEXT) {
#pragma unroll
        for (int ct = 0; ct < 4; ct++)
#pragma unroll
            for (int r = 0; r < 4; r++) {
                float v = fmaxf(acc[ct][r] + b2s[ct * 16 + colb], 0.0f);
                t2[w * 16 + ((lane >> 4) << 2) + r][ct * 16 + colb] = f2bf(v);
            }
        __syncthreads();
        f32x4 acc2[4] = {{0,0,0,0},{0,0,0,0},{0,0,0,0},{0,0,0,0}};
#pragma unroll
        for (int ks = 0; ks < 2; ks++) {
            short8 af2 = *(const short8*)&t2[w * 16 + (lane & 15)][ks * 32 + k0base];
#pragma unroll
            for (int ct = 0; ct < 4; ct++) {
                short8 bf = *(const short8*)&wnf[ks][ct][lane][0];
                acc2[ct] = __builtin_amdgcn_mfma_f32_16x16x32_bf16(af2, bf, acc2[ct], 0, 0, 0);
            }
        }
        __syncthreads();
#pragma unroll
        for (int ct = 0; ct < 4; ct++)
#pragma unroll
            for (int r = 0; r < 4; r++)
                t2[w * 16 + ((lane >> 4) << 2) + r][ct * 16 + colb] = f2bf(acc2[ct][r]);
        __syncthreads();
        int row = threadIdx.x >> 2, seg = threadIdx.x & 3;
        if (row0 + row < n) {
            const uint4* p = (const uint4*)&t2[row][seg * 16];
            uint4 v0 = p[0], v1 = p[1];
            ushort_t* plane = (seg < 2) ? Ylo : Yhi;
            uint4* q = (uint4*)(plane + (size_t)(row0 + row) * 32 + (seg & 1) * 16);
            q[0] = v0; q[1] = v1;
        }
    } else {
#pragma unroll
        for (int ct = 0; ct < 4; ct++)
#pragma unroll
            for (int r = 0; r < 4; r++) {
                int row = row0 + w * 16 + ((lane >> 4) << 2) + r;
                if (row < n) {
                    float v = fmaxf(acc[ct][r] + b2s[ct * 16 + colb], 0.0f);
                    Hout[(size_t)row * 64 + ct * 16 + colb] = v;
                }
            }
    }
}

// ================= mean pool, exploiting sorted batch =================
__global__ __launch_bounds__(64) void pool_sorted(const float* __restrict__ h,
                                                  const int* __restrict__ batch,
                                                  float* __restrict__ sums,
                                                  int* __restrict__ cnt, int n) {
    int lane = threadIdx.x;
    int start = blockIdx.x * 64;
    int end = min(start + 64, n);
    if (start >= end) return;
    int cur = batch[start];
    float acc = 0.0f;
    int c = 0;
    for (int i = start; i < end; i++) {
        int b = batch[i];
        if (b != cur) {
            atomicAdd(&sums[cur * 64 + lane], acc);
            if (lane == 0) atomicAdd(&cnt[cur], c);
            acc = 0.0f; c = 0; cur = b;
        }
        acc += h[(size_t)i * 64 + lane];
        c++;
    }
    atomicAdd(&sums[cur * 64 + lane], acc);
    if (lane == 0) atomicAdd(&cnt[cur], c);
}

// ================= finalize =================
__global__ __launch_bounds__(64) void finalize_kernel(const float* __restrict__ sums,
                                                      const int* __restrict__ cnt,
                                                      const float* __restrict__ Wl,
                                                      const float* __restrict__ bl,
                                                      float* __restrict__ out, int G) {
    int g = blockIdx.x;
    int j = threadIdx.x;
    __shared__ float gs[64];
    float c = (float)max(cnt[g], 1);
    float v = sums[g * 64 + j] / c;
    gs[j] = v;
    out[G * 2 + g * 64 + j] = v;
    __syncthreads();
    if (j < 2) {
        float acc = bl[j];
#pragma unroll
        for (int k = 0; k < 64; k++) acc += gs[k] * Wl[k * 2 + j];
        out[g * 2 + j] = acc;
    }
}

extern "C" void kernel_launch(void* const* d_in, const int* in_sizes, int n_in,
                              void* d_out, int out_size, void* d_ws, size_t ws_size,
                              hipStream_t stream) {
    const float* x     = (const float*)d_in[0];
    const int*   ei    = (const int*)d_in[1];
    const int*   batch = (const int*)d_in[2];
    const float* W1_0 = (const float*)d_in[3];
    const float* b1_0 = (const float*)d_in[4];
    const float* W2_0 = (const float*)d_in[5];
    const float* b2_0 = (const float*)d_in[6];
    const float* W1_1 = (const float*)d_in[7];
    const float* b1_1 = (const float*)d_in[8];
    const float* W2_1 = (const float*)d_in[9];
    const float* b2_1 = (const float*)d_in[10];
    const float* W1_2 = (const float*)d_in[11];
    const float* b1_2 = (const float*)d_in[12];
    const float* W2_2 = (const float*)d_in[13];
    const float* b2_2 = (const float*)d_in[14];
    const float* Wl   = (const float*)d_in[15];
    const float* bl   = (const float*)d_in[16];

    const int N = in_sizes[0] / 128;
    const int E = in_sizes[1] / 2;
    const int G = out_size / 66;
    const int* src = ei;
    const int* dst = ei + E;
    float* out = (float*)d_out;

    const int nb = (N + 1023) / 1024;

    // ---- workspace layout ----
    float* H      = (float*)d_ws;                       // N*64 f32
    ushort_t* Ylo = (ushort_t*)(H + (size_t)N * 64);    // N*32 bf16
    ushort_t* Yhi = Ylo + (size_t)N * 32;
    ushort_t* Zlo = Yhi + (size_t)N * 32;
    ushort_t* Zhi = Zlo + (size_t)N * 32;
    float* sums   = (float*)(Zhi + (size_t)N * 32);     // G*64
    int*   cnt    = (int*)(sums + (size_t)G * 64);      // G
    int*   deg    = cnt + G;                            // N
    int*   rowptr = deg + N;                            // N+1
    int*   col    = rowptr + (N + 1);                   // E
    int*   rank   = col + E;                            // E
    int*   bsum   = rank + E;                           // nb

    // ---- zero: sums|cnt|deg contiguous -> one memset ----
    hipMemsetAsync(sums, 0, ((size_t)G * 64 + G + N) * sizeof(int), stream);

    // ---- CSR build ----
    hist_rank<<<(E + 255) / 256, 256, 0, stream>>>(dst, deg, rank, E);
    scan_reduce<<<nb, 256, 0, stream>>>(deg, bsum, N);
    scan_bsum<<<1, 64, 0, stream>>>(bsum, nb, rowptr, N);
    scan_final<<<nb, 256, 0, stream>>>(deg, bsum, rowptr, N);
    const int SUBS = 64;
    const int CE = (E + SUBS - 1) / SUBS;
    fill_range<<<8 * SUBS, 256, 0, stream>>>(src, dst, rank, rowptr, col, E, CE);

    const int mblk = (N + 63) / 64;

    // ---- layer 0 ----
    gemm_y_mfma<<<mblk, 256, 0, stream>>>(x, W1_0, Ylo, Yhi, N);
    gather_half<<<mblk, 256, 0, stream>>>(Ylo, rowptr, col, Zlo, N);
    gather_half<<<mblk, 256, 0, stream>>>(Yhi, rowptr, col, Zhi, N);
    fuse_mfma<1><<<mblk, 256, 0, stream>>>(Zlo, Zhi, b1_0, W2_0, b2_0, W1_1, Ylo, Yhi, nullptr, N);
    // ---- layer 1 ----
    gather_half<<<mblk, 256, 0, stream>>>(Ylo, rowptr, col, Zlo, N);
    gather_half<<<mblk, 256, 0, stream>>>(Yhi, rowptr, col, Zhi, N);
    fuse_mfma<1><<<mblk, 256, 0, stream>>>(Zlo, Zhi, b1_1, W2_1, b2_1, W1_2, Ylo, Yhi, nullptr, N);
    // ---- layer 2 ----
    gather_half<<<mblk, 256, 0, stream>>>(Ylo, rowptr, col, Zlo, N);
    gather_half<<<mblk, 256, 0, stream>>>(Yhi, rowptr, col, Zhi, N);
    fuse_mfma<0><<<mblk, 256, 0, stream>>>(Zlo, Zhi, b1_2, W2_2, b2_2, nullptr, nullptr, nullptr, H, N);
    // ---- pool + head ----
    pool_sorted<<<(N + 63) / 64, 64, 0, stream>>>(H, batch, sums, cnt, N);
    finalize_kernel<<<G, 64, 0, stream>>>(sums, cnt, Wl, bl, out, G);
}

// Round 8
// 205.269 us; speedup vs baseline: 2.6724x; 1.1848x over previous
//
#include <hip/hip_runtime.h>

typedef unsigned short ushort_t;
typedef __attribute__((ext_vector_type(8))) short short8;
typedef __attribute__((ext_vector_type(4))) float f32x4;

__device__ inline float bflo(unsigned int u) { return __uint_as_float(u << 16); }
__device__ inline float bfhi(unsigned int u) { return __uint_as_float(u & 0xFFFF0000u); }
__device__ inline unsigned short f2bf(float f) {
    unsigned int u = __float_as_uint(f);
    return (unsigned short)((u + 0x7FFFu + ((u >> 16) & 1u)) >> 16);
}

union U16B { uint4 u; short8 s; };

// ================= CSR build =================
__global__ __launch_bounds__(256) void hist_rank(const int* __restrict__ dst,
                                                 int* __restrict__ deg,
                                                 int* __restrict__ rank, int E) {
    int e = blockIdx.x * 256 + threadIdx.x;
    if (e < E) rank[e] = atomicAdd(&deg[dst[e]], 1);
}

__global__ __launch_bounds__(256) void scan_reduce(const int* __restrict__ deg,
                                                   int* __restrict__ bsum, int n) {
    __shared__ int sdata[256];
    int base = blockIdx.x * 1024 + threadIdx.x * 4;
    int s = 0;
#pragma unroll
    for (int k = 0; k < 4; k++) { int i = base + k; if (i < n) s += deg[i]; }
    sdata[threadIdx.x] = s;
    __syncthreads();
    for (int off = 128; off > 0; off >>= 1) {
        if (threadIdx.x < off) sdata[threadIdx.x] += sdata[threadIdx.x + off];
        __syncthreads();
    }
    if (threadIdx.x == 0) bsum[blockIdx.x] = sdata[0];
}

__global__ void scan_bsum(int* __restrict__ bsum, int nb, int* __restrict__ rowptr, int n) {
    if (threadIdx.x == 0 && blockIdx.x == 0) {
        int acc = 0;
        for (int i = 0; i < nb; i++) { int v = bsum[i]; bsum[i] = acc; acc += v; }
        rowptr[n] = acc;
    }
}

__global__ __launch_bounds__(256) void scan_final(const int* __restrict__ deg,
                                                  const int* __restrict__ bsum,
                                                  int* __restrict__ rowptr, int n) {
    __shared__ int sdata[256];
    int t = threadIdx.x;
    int base = blockIdx.x * 1024 + t * 4;
    int v[4]; int s = 0;
#pragma unroll
    for (int k = 0; k < 4; k++) { int i = base + k; v[k] = (i < n) ? deg[i] : 0; s += v[k]; }
    sdata[t] = s;
    __syncthreads();
    for (int off = 1; off < 256; off <<= 1) {
        int x = 0;
        if (t >= off) x = sdata[t - off];
        __syncthreads();
        if (t >= off) sdata[t] += x;
        __syncthreads();
    }
    int off = bsum[blockIdx.x] + sdata[t] - s;
#pragma unroll
    for (int k = 0; k < 4; k++) {
        int i = base + k;
        if (i < n) { rowptr[i] = off; off += v[k]; }
    }
}

// Range-partitioned fill: block's dst-range = blockIdx&7; col-slice per range
// ~0.4 MB -> L2-resident dirty lines. Slot rowptr[d]+rank[e] unique per edge.
__global__ __launch_bounds__(256) void fill_range(const int* __restrict__ src,
                                                  const int* __restrict__ dst,
                                                  const int* __restrict__ rank,
                                                  const int* __restrict__ rowptr,
                                                  int* __restrict__ col, int E, int CE) {
    int range = blockIdx.x & 7;
    int sub = blockIdx.x >> 3;
    int e0 = sub * CE;
    int e1 = min(e0 + CE, E);
    for (int e = e0 + threadIdx.x; e < e1; e += 256) {
        int d = dst[e];
        if ((d >> 13) == range) col[rowptr[d] + rank[e]] = src[e];
    }
}

// ================= MFMA GEMM: Y = bf16(x @ W1) =================
__global__ __launch_bounds__(256) void gemm_y_mfma(const float* __restrict__ x,
                                                   const float* __restrict__ W1,
                                                   ushort_t* __restrict__ Y, int n) {
    __shared__ ushort_t w1f[4][4][64][8];
    __shared__ ushort_t ybuf[64][72];
    for (int i = threadIdx.x; i < 8192; i += 256) {
        int j = i & 7, lane = (i >> 3) & 63, ct = (i >> 9) & 3, ks = (i >> 11) & 3;
        int k = ks * 32 + ((lane >> 4) << 3) + j;
        int c = ct * 16 + (lane & 15);
        w1f[ks][ct][lane][j] = f2bf(W1[k * 64 + c]);
    }
    __syncthreads();
    int w = threadIdx.x >> 6, lane = threadIdx.x & 63;
    int row0 = blockIdx.x * 64;
    int arow = row0 + w * 16 + (lane & 15);
    if (arow >= n) arow = n - 1;
    const float* xr = x + (size_t)arow * 128;
    int k0base = (lane >> 4) << 3;

    f32x4 acc[4] = {{0,0,0,0},{0,0,0,0},{0,0,0,0},{0,0,0,0}};
#pragma unroll
    for (int ks = 0; ks < 4; ks++) {
        int k0 = ks * 32 + k0base;
        float4 aa = *(const float4*)(xr + k0);
        float4 ab = *(const float4*)(xr + k0 + 4);
        U16B af;
        af.u.x = (unsigned int)f2bf(aa.x) | ((unsigned int)f2bf(aa.y) << 16);
        af.u.y = (unsigned int)f2bf(aa.z) | ((unsigned int)f2bf(aa.w) << 16);
        af.u.z = (unsigned int)f2bf(ab.x) | ((unsigned int)f2bf(ab.y) << 16);
        af.u.w = (unsigned int)f2bf(ab.z) | ((unsigned int)f2bf(ab.w) << 16);
#pragma unroll
        for (int ct = 0; ct < 4; ct++) {
            short8 bf = *(const short8*)&w1f[ks][ct][lane][0];
            acc[ct] = __builtin_amdgcn_mfma_f32_16x16x32_bf16(af.s, bf, acc[ct], 0, 0, 0);
        }
    }
#pragma unroll
    for (int ct = 0; ct < 4; ct++)
#pragma unroll
        for (int r = 0; r < 4; r++)
            ybuf[w * 16 + ((lane >> 4) << 2) + r][ct * 16 + (lane & 15)] = f2bf(acc[ct][r]);
    __syncthreads();
    int row = threadIdx.x >> 2, seg = threadIdx.x & 3;
    if (row0 + row < n) {
        const uint4* p = (const uint4*)&ybuf[row][seg * 16];
        uint4 v0 = p[0], v1 = p[1];
        uint4* q = (uint4*)(Y + (size_t)(row0 + row) * 64 + seg * 16);
        q[0] = v0; q[1] = v1;
    }
}

// ================= gather: full 128 B bf16 rows (transaction-optimal) =================
__global__ __launch_bounds__(256) void gather_bf16(const ushort_t* __restrict__ Y,
                                                   const int* __restrict__ rowptr,
                                                   const int* __restrict__ col,
                                                   ushort_t* __restrict__ Z, int n) {
    int lane = threadIdx.x & 63;
    int sub = lane >> 3;
    int sl  = lane & 7;
    int node = blockIdx.x * 32 + (threadIdx.x >> 6) * 8 + sub;
    if (node >= n) return;
    int e  = rowptr[node];
    int e1 = rowptr[node + 1];

    float a[8];
    {
        uint4 v = *(const uint4*)(Y + (size_t)node * 64 + sl * 8);
        a[0] = bflo(v.x); a[1] = bfhi(v.x);
        a[2] = bflo(v.y); a[3] = bfhi(v.y);
        a[4] = bflo(v.z); a[5] = bfhi(v.z);
        a[6] = bflo(v.w); a[7] = bfhi(v.w);
    }
    while (e + 1 < e1) {
        int c0 = col[e], c1 = col[e + 1];
        uint4 v0 = *(const uint4*)(Y + (size_t)c0 * 64 + sl * 8);
        uint4 v1 = *(const uint4*)(Y + (size_t)c1 * 64 + sl * 8);
        a[0] += bflo(v0.x) + bflo(v1.x); a[1] += bfhi(v0.x) + bfhi(v1.x);
        a[2] += bflo(v0.y) + bflo(v1.y); a[3] += bfhi(v0.y) + bfhi(v1.y);
        a[4] += bflo(v0.z) + bflo(v1.z); a[5] += bfhi(v0.z) + bfhi(v1.z);
        a[6] += bflo(v0.w) + bflo(v1.w); a[7] += bfhi(v0.w) + bfhi(v1.w);
        e += 2;
    }
    if (e < e1) {
        uint4 v0 = *(const uint4*)(Y + (size_t)col[e] * 64 + sl * 8);
        a[0] += bflo(v0.x); a[1] += bfhi(v0.x);
        a[2] += bflo(v0.y); a[3] += bfhi(v0.y);
        a[4] += bflo(v0.z); a[5] += bfhi(v0.z);
        a[6] += bflo(v0.w); a[7] += bfhi(v0.w);
    }
    uint4 o;
    o.x = (unsigned int)f2bf(a[0]) | ((unsigned int)f2bf(a[1]) << 16);
    o.y = (unsigned int)f2bf(a[2]) | ((unsigned int)f2bf(a[3]) << 16);
    o.z = (unsigned int)f2bf(a[4]) | ((unsigned int)f2bf(a[5]) << 16);
    o.w = (unsigned int)f2bf(a[6]) | ((unsigned int)f2bf(a[7]) << 16);
    *(uint4*)(Z + (size_t)node * 64 + sl * 8) = o;
}

// ================= fused MLP via MFMA (+pool fusion on last layer) =================
template <int HASNEXT>
__global__ __launch_bounds__(256) void fuse_mfma(const ushort_t* __restrict__ Z,
                                                 const float* __restrict__ b1,
                                                 const float* __restrict__ W2,
                                                 const float* __restrict__ b2,
                                                 const float* __restrict__ Wn,
                                                 ushort_t* __restrict__ Yn,
                                                 const int* __restrict__ batch,
                                                 float* __restrict__ sums, int n) {
    __shared__ ushort_t w2f[2][4][64][8];
    __shared__ ushort_t wnf[HASNEXT ? 2 : 1][4][64][8];
    __shared__ ushort_t t2[64][72];
    __shared__ float vbuf[HASNEXT ? 1 : 64][65];
    __shared__ float b1s[64], b2s[64];
    for (int i = threadIdx.x; i < 4096; i += 256) {
        int j = i & 7, lane = (i >> 3) & 63, ct = (i >> 9) & 3, ks = (i >> 11) & 1;
        int k = ks * 32 + ((lane >> 4) << 3) + j;
        int c = ct * 16 + (lane & 15);
        w2f[ks][ct][lane][j] = f2bf(W2[k * 64 + c]);
        if (HASNEXT) wnf[ks][ct][lane][j] = f2bf(Wn[k * 64 + c]);
    }
    if (threadIdx.x < 64) { b1s[threadIdx.x] = b1[threadIdx.x]; b2s[threadIdx.x] = b2[threadIdx.x]; }
    __syncthreads();

    int w = threadIdx.x >> 6, lane = threadIdx.x & 63;
    int row0 = blockIdx.x * 64;
    int arow = row0 + w * 16 + (lane & 15);
    if (arow >= n) arow = n - 1;
    const ushort_t* zr = Z + (size_t)arow * 64;
    int k0base = (lane >> 4) << 3;

    f32x4 acc[4] = {{0,0,0,0},{0,0,0,0},{0,0,0,0},{0,0,0,0}};
#pragma unroll
    for (int ks = 0; ks < 2; ks++) {
        int k0 = ks * 32 + k0base;
        uint4 zv = *(const uint4*)(zr + k0);
        float e0 = fmaxf(bflo(zv.x) + b1s[k0 + 0], 0.0f);
        float e1 = fmaxf(bfhi(zv.x) + b1s[k0 + 1], 0.0f);
        float e2 = fmaxf(bflo(zv.y) + b1s[k0 + 2], 0.0f);
        float e3 = fmaxf(bfhi(zv.y) + b1s[k0 + 3], 0.0f);
        float e4 = fmaxf(bflo(zv.z) + b1s[k0 + 4], 0.0f);
        float e5 = fmaxf(bfhi(zv.z) + b1s[k0 + 5], 0.0f);
        float e6 = fmaxf(bflo(zv.w) + b1s[k0 + 6], 0.0f);
        float e7 = fmaxf(bfhi(zv.w) + b1s[k0 + 7], 0.0f);
        U16B af;
        af.u.x = (unsigned int)f2bf(e0) | ((unsigned int)f2bf(e1) << 16);
        af.u.y = (unsigned int)f2bf(e2) | ((unsigned int)f2bf(e3) << 16);
        af.u.z = (unsigned int)f2bf(e4) | ((unsigned int)f2bf(e5) << 16);
        af.u.w = (unsigned int)f2bf(e6) | ((unsigned int)f2bf(e7) << 16);
#pragma unroll
        for (int ct = 0; ct < 4; ct++) {
            short8 bf = *(const short8*)&w2f[ks][ct][lane][0];
            acc[ct] = __builtin_amdgcn_mfma_f32_16x16x32_bf16(af.s, bf, acc[ct], 0, 0, 0);
        }
    }

    int colb = lane & 15;
    if (HASNEXT) {
#pragma unroll
        for (int ct = 0; ct < 4; ct++)
#pragma unroll
            for (int r = 0; r < 4; r++) {
                float v = fmaxf(acc[ct][r] + b2s[ct * 16 + colb], 0.0f);
                t2[w * 16 + ((lane >> 4) << 2) + r][ct * 16 + colb] = f2bf(v);
            }
        __syncthreads();
        f32x4 acc2[4] = {{0,0,0,0},{0,0,0,0},{0,0,0,0},{0,0,0,0}};
#pragma unroll
        for (int ks = 0; ks < 2; ks++) {
            short8 af2 = *(const short8*)&t2[w * 16 + (lane & 15)][ks * 32 + k0base];
#pragma unroll
            for (int ct = 0; ct < 4; ct++) {
                short8 bf = *(const short8*)&wnf[ks][ct][lane][0];
                acc2[ct] = __builtin_amdgcn_mfma_f32_16x16x32_bf16(af2, bf, acc2[ct], 0, 0, 0);
            }
        }
        __syncthreads();
#pragma unroll
        for (int ct = 0; ct < 4; ct++)
#pragma unroll
            for (int r = 0; r < 4; r++)
                t2[w * 16 + ((lane >> 4) << 2) + r][ct * 16 + colb] = f2bf(acc2[ct][r]);
        __syncthreads();
        int row = threadIdx.x >> 2, seg = threadIdx.x & 3;
        if (row0 + row < n) {
            const uint4* p = (const uint4*)&t2[row][seg * 16];
            uint4 v0 = p[0], v1 = p[1];
            uint4* q = (uint4*)(Yn + (size_t)(row0 + row) * 64 + seg * 16);
            q[0] = v0; q[1] = v1;
        }
    } else {
        // last layer: v -> LDS f32, then segmented (sorted-batch) pool reduce.
#pragma unroll
        for (int ct = 0; ct < 4; ct++)
#pragma unroll
            for (int r = 0; r < 4; r++) {
                float v = fmaxf(acc[ct][r] + b2s[ct * 16 + colb], 0.0f);
                vbuf[w * 16 + ((lane >> 4) << 2) + r][ct * 16 + colb] = v;
            }
        __syncthreads();
        int j  = threadIdx.x & 63;
        int i0 = (threadIdx.x >> 6) * 16;
        int cur = -1; float a = 0.0f;
        for (int i = i0; i < i0 + 16; i++) {
            int row = row0 + i;
            if (row >= n) break;
            int b = batch[row];
            if (b != cur) {
                if (cur >= 0) atomicAdd(&sums[cur * 64 + j], a);
                cur = b; a = 0.0f;
            }
            a += vbuf[i][j];
        }
        if (cur >= 0) atomicAdd(&sums[cur * 64 + j], a);
    }
}

// ================= finalize: cnt via binary search on sorted batch =================
__global__ __launch_bounds__(64) void finalize_kernel(const float* __restrict__ sums,
                                                      const int* __restrict__ batch, int n,
                                                      const float* __restrict__ Wl,
                                                      const float* __restrict__ bl,
                                                      float* __restrict__ out, int G) {
    int g = blockIdx.x;
    int j = threadIdx.x;
    __shared__ float gs[64];
    int lo = 0, hi = n;
    while (lo < hi) { int m = (lo + hi) >> 1; if (batch[m] < g) lo = m + 1; else hi = m; }
    int lo2 = lo, hi2 = n;
    while (lo2 < hi2) { int m = (lo2 + hi2) >> 1; if (batch[m] < g + 1) lo2 = m + 1; else hi2 = m; }
    float c = (float)max(lo2 - lo, 1);
    float v = sums[g * 64 + j] / c;
    gs[j] = v;
    out[G * 2 + g * 64 + j] = v;
    __syncthreads();
    if (j < 2) {
        float acc = bl[j];
#pragma unroll
        for (int k = 0; k < 64; k++) acc += gs[k] * Wl[k * 2 + j];
        out[g * 2 + j] = acc;
    }
}

extern "C" void kernel_launch(void* const* d_in, const int* in_sizes, int n_in,
                              void* d_out, int out_size, void* d_ws, size_t ws_size,
                              hipStream_t stream) {
    const float* x     = (const float*)d_in[0];
    const int*   ei    = (const int*)d_in[1];
    const int*   batch = (const int*)d_in[2];
    const float* W1_0 = (const float*)d_in[3];
    const float* b1_0 = (const float*)d_in[4];
    const float* W2_0 = (const float*)d_in[5];
    const float* b2_0 = (const float*)d_in[6];
    const float* W1_1 = (const float*)d_in[7];
    const float* b1_1 = (const float*)d_in[8];
    const float* W2_1 = (const float*)d_in[9];
    const float* b2_1 = (const float*)d_in[10];
    const float* W1_2 = (const float*)d_in[11];
    const float* b1_2 = (const float*)d_in[12];
    const float* W2_2 = (const float*)d_in[13];
    const float* b2_2 = (const float*)d_in[14];
    const float* Wl   = (const float*)d_in[15];
    const float* bl   = (const float*)d_in[16];

    const int N = in_sizes[0] / 128;
    const int E = in_sizes[1] / 2;
    const int G = out_size / 66;
    const int* src = ei;
    const int* dst = ei + E;
    float* out = (float*)d_out;

    const int nb = (N + 1023) / 1024;

    // ---- workspace layout ----
    ushort_t* Y   = (ushort_t*)d_ws;                    // N*64 bf16
    ushort_t* Z   = Y + (size_t)N * 64;                 // N*64 bf16
    float* sums   = (float*)(Z + (size_t)N * 64);       // G*64 f32
    int*   deg    = (int*)(sums + (size_t)G * 64);      // N
    int*   rowptr = deg + N;                            // N+1
    int*   col    = rowptr + (N + 1);                   // E
    int*   rank   = col + E;                            // E
    int*   bsum   = rank + E;                           // nb

    // ---- zero sums+deg (contiguous) ----
    hipMemsetAsync(sums, 0, ((size_t)G * 64 + N) * sizeof(int), stream);

    // ---- CSR build ----
    hist_rank<<<(E + 255) / 256, 256, 0, stream>>>(dst, deg, rank, E);
    scan_reduce<<<nb, 256, 0, stream>>>(deg, bsum, N);
    scan_bsum<<<1, 64, 0, stream>>>(bsum, nb, rowptr, N);
    scan_final<<<nb, 256, 0, stream>>>(deg, bsum, rowptr, N);
    const int SUBS = 64;
    const int CE = (E + SUBS - 1) / SUBS;
    fill_range<<<8 * SUBS, 256, 0, stream>>>(src, dst, rank, rowptr, col, E, CE);

    const int mblk = (N + 63) / 64;
    const int gblk = (N + 31) / 32;

    // ---- layer 0 ----
    gemm_y_mfma<<<mblk, 256, 0, stream>>>(x, W1_0, Y, N);
    gather_bf16<<<gblk, 256, 0, stream>>>(Y, rowptr, col, Z, N);
    fuse_mfma<1><<<mblk, 256, 0, stream>>>(Z, b1_0, W2_0, b2_0, W1_1, Y, nullptr, nullptr, N);
    // ---- layer 1 ----
    gather_bf16<<<gblk, 256, 0, stream>>>(Y, rowptr, col, Z, N);
    fuse_mfma<1><<<mblk, 256, 0, stream>>>(Z, b1_1, W2_1, b2_1, W1_2, Y, nullptr, nullptr, N);
    // ---- layer 2 (pool fused) ----
    gather_bf16<<<gblk, 256, 0, stream>>>(Y, rowptr, col, Z, N);
    fuse_mfma<0><<<mblk, 256, 0, stream>>>(Z, b1_2, W2_2, b2_2, nullptr, nullptr, batch, sums, N);
    // ---- head ----
    finalize_kernel<<<G, 64, 0, stream>>>(sums, batch, N, Wl, bl, out, G);
}